// Round 3
// baseline (1555.374 us; speedup 1.0000x reference)
//
#include <hip/hip_runtime.h>
#include <hip/hip_bf16.h>
#include <math.h>

// ---------------- constants (problem is fixed-shape) ----------------
// B=2, H=W=256, L=65536, C=180, NH=6, hd=30, WS=8, hd_ffn=360
// I/O dtype: fp32 (per reference). Internals: bf16 (MFMA), fp32 accum.
#define BATCH 2
#define IMG 256
#define LTOK 65536
#define CH 180
#define BL (BATCH * LTOK)            // 131072 tokens
#define HDF 360

using frag_ab = __attribute__((ext_vector_type(8))) short;   // 8 bf16 in 4 VGPRs
using frag_cd = __attribute__((ext_vector_type(4))) float;   // 4 f32 acc

__device__ __forceinline__ float b2f(unsigned short u) {
    union { unsigned int i; float f; } v; v.i = ((unsigned int)u) << 16; return v.f;
}
__device__ __forceinline__ unsigned short f2b(float f) {
    union { float f; unsigned int i; } v; v.f = f;
    unsigned int x = v.i;
    unsigned int r = (x + 0x7fffu + ((x >> 16) & 1u)) >> 16;   // RNE
    return (unsigned short)r;
}
__device__ __forceinline__ float gelu_f(float x) {
    return 0.5f * x * (1.0f + erff(x * 0.70710678118654752f));
}
// dtype-polymorphic load/store helpers
__device__ __forceinline__ float ldv(float v) { return v; }
__device__ __forceinline__ float ldv(unsigned short v) { return b2f(v); }
__device__ __forceinline__ void stv(float* p, float v) { *p = v; }
__device__ __forceinline__ void stv(unsigned short* p, float v) { *p = f2b(v); }

// ---------------- fp32 -> bf16 weight conversion (one-shot) ----------------
// segments: w_qkv 97200 | w_proj 32400 | ffn_w1 64800 | ffn_w2 64800 = 259200
__global__ __launch_bounds__(256) void convw_kernel(
    const float* __restrict__ a, const float* __restrict__ b,
    const float* __restrict__ c, const float* __restrict__ d,
    unsigned short* __restrict__ out)
{
    int g = blockIdx.x * 256 + threadIdx.x;
    float v;
    if      (g < 97200)  v = a[g];
    else if (g < 129600) v = b[g - 97200];
    else if (g < 194400) v = c[g - 129600];
    else if (g < 259200) v = d[g - 194400];
    else return;
    out[g] = f2b(v);
}

// ---------------- LayerNorm: one wave per token (C=180) ----------------
template <typename TIN>
__global__ __launch_bounds__(256) void ln_kernel(
    const TIN* __restrict__ x, const float* __restrict__ g,
    const float* __restrict__ bta, unsigned short* __restrict__ out)
{
    int wave = threadIdx.x >> 6, lane = threadIdx.x & 63;
    int tok = blockIdx.x * 4 + wave;
    const TIN* row = x + (size_t)tok * CH;
    float v0 = ldv(row[lane]);
    float v1 = ldv(row[lane + 64]);
    float v2 = (lane < CH - 128) ? ldv(row[lane + 128]) : 0.f;
    float s = v0 + v1 + v2;
    float sq = v0 * v0 + v1 * v1 + v2 * v2;
    #pragma unroll
    for (int off = 32; off > 0; off >>= 1) {
        s += __shfl_xor(s, off);
        sq += __shfl_xor(sq, off);
    }
    float mean = s * (1.f / CH);
    float var = sq * (1.f / CH) - mean * mean;
    float rstd = rsqrtf(var + 1e-5f);
    unsigned short* orow = out + (size_t)tok * CH;
    orow[lane]      = f2b((v0 - mean) * rstd * g[lane]       + bta[lane]);
    orow[lane + 64] = f2b((v1 - mean) * rstd * g[lane + 64]  + bta[lane + 64]);
    if (lane < CH - 128)
        orow[lane + 128] = f2b((v2 - mean) * rstd * g[lane + 128] + bta[lane + 128]);
}

// ---------------- generic MFMA GEMM ----------------
// Y[M][N] = act( X[M][K] @ W[N][K]^T + bias ) (+ res bf16); TOUT in {ushort,float}
// 64x64 tile per block, 256 threads (4 waves), wave w owns n-cols [w*16,w*16+16).
// layouts (learn_hip m89/m91): A[m=l&15][k=(l>>4)*8+j], B[k][n=l&15], D[row=(l>>4)*4+r][col=l&15]
template <int ACT, bool HAS_BIAS, bool HAS_RES, typename TOUT>
__global__ __launch_bounds__(256) void gemm_kernel(
    const unsigned short* __restrict__ X, int ldx,
    const unsigned short* __restrict__ Wt,
    const float* __restrict__ bias,
    const unsigned short* __restrict__ res, int ldr,
    TOUT* __restrict__ Y, int ldy,
    int N, int K)
{
    __shared__ unsigned short Xs[64][40];   // pad 32->40: 80B rows, 16B-aligned frags
    __shared__ unsigned short Ws[64][40];
    const int tid = threadIdx.x;
    const int wave = tid >> 6;
    const int lane = tid & 63;
    const int l16 = lane & 15;
    const int q = lane >> 4;
    const int m0 = blockIdx.x * 64;
    const int n0 = blockIdx.y * 64;
    const int lr = tid >> 2;          // 0..63 row of tile
    const int lk = (tid & 3) << 3;    // 0,8,16,24

    frag_cd acc[4];
    #pragma unroll
    for (int i = 0; i < 4; ++i) acc[i] = (frag_cd){0.f, 0.f, 0.f, 0.f};

    for (int k0 = 0; k0 < K; k0 += 32) {
        const bool kfull = (k0 + 32 <= K);
        { // X tile (M multiple of 64, rows always valid)
            const unsigned short* p = X + (size_t)(m0 + lr) * ldx + (k0 + lk);
            if (kfull) {
                *(uint2*)&Xs[lr][lk]     = *(const uint2*)p;
                *(uint2*)&Xs[lr][lk + 4] = *(const uint2*)(p + 4);
            } else {
                #pragma unroll
                for (int j = 0; j < 8; ++j)
                    Xs[lr][lk + j] = (k0 + lk + j < K) ? p[j] : (unsigned short)0;
            }
        }
        { // W tile
            const int n = n0 + lr;
            const unsigned short* p = Wt + (size_t)n * K + (k0 + lk);
            if (n < N && kfull) {
                *(uint2*)&Ws[lr][lk]     = *(const uint2*)p;
                *(uint2*)&Ws[lr][lk + 4] = *(const uint2*)(p + 4);
            } else {
                #pragma unroll
                for (int j = 0; j < 8; ++j)
                    Ws[lr][lk + j] = (n < N && (k0 + lk + j) < K) ? p[j] : (unsigned short)0;
            }
        }
        __syncthreads();
        frag_ab bfr = *(const frag_ab*)&Ws[wave * 16 + l16][q * 8];
        #pragma unroll
        for (int mb = 0; mb < 4; ++mb) {
            frag_ab afr = *(const frag_ab*)&Xs[mb * 16 + l16][q * 8];
            acc[mb] = __builtin_amdgcn_mfma_f32_16x16x32_bf16(afr, bfr, acc[mb], 0, 0, 0);
        }
        __syncthreads();
    }
    const int col = n0 + wave * 16 + l16;
    if (col < N) {
        float bv = 0.f;
        if (HAS_BIAS) bv = bias[col];
        #pragma unroll
        for (int mb = 0; mb < 4; ++mb) {
            #pragma unroll
            for (int r = 0; r < 4; ++r) {
                int row = m0 + mb * 16 + q * 4 + r;
                float v = acc[mb][r] + bv;
                if (ACT == 1) v = gelu_f(v);
                if (HAS_RES) v += b2f(res[(size_t)row * ldr + col]);
                stv(&Y[(size_t)row * ldy + col], v);
            }
        }
    }
}

// ---------------- window attention (one window per block, loop 6 heads) ----------------
// qkv row layout (540, bf16): [q: h*30+d][k: 180+h*30+d][v: 360+h*30+d]; b_rel fp32
__global__ __launch_bounds__(256) void attn_kernel(
    const unsigned short* __restrict__ qkv,
    const float* __restrict__ b_rel,
    unsigned short* __restrict__ attn_out)
{
    __shared__ float qs[64][33], ks[64][33], vs[64][33];
    __shared__ float S[64][65];
    const int tid = threadIdx.x;
    const int wid = blockIdx.x;              // 0..2047
    const int b = wid >> 10;                 // 1024 windows per image
    const int wy = (wid & 1023) >> 5;
    const int wx = wid & 31;
    const float scale = 0.18257418583505536f;  // 30^-0.5
    const int ty = tid >> 4, tx = tid & 15;

    for (int h = 0; h < 6; ++h) {
        for (int idx = tid; idx < 64 * 32; idx += 256) {
            int r = idx >> 5, d = idx & 31;
            float qv = 0.f, kv = 0.f, vv = 0.f;
            if (d < 30) {
                int l = ((wy << 3) + (r >> 3)) * IMG + (wx << 3) + (r & 7);
                const unsigned short* rowp = qkv + (size_t)(b * LTOK + l) * 540 + h * 30 + d;
                qv = b2f(rowp[0]); kv = b2f(rowp[180]); vv = b2f(rowp[360]);
            }
            qs[r][d] = qv; ks[r][d] = kv; vs[r][d] = vv;
        }
        __syncthreads();
        { // S = (q*scale) @ k^T + b_rel : 4x4 tile per thread
            float a4[4][4] = {{0.f}};
            for (int d = 0; d < 30; ++d) {
                float qv[4], kv[4];
                #pragma unroll
                for (int i = 0; i < 4; ++i) qv[i] = qs[ty * 4 + i][d];
                #pragma unroll
                for (int j = 0; j < 4; ++j) kv[j] = ks[tx * 4 + j][d];
                #pragma unroll
                for (int i = 0; i < 4; ++i)
                    #pragma unroll
                    for (int j = 0; j < 4; ++j) a4[i][j] += qv[i] * kv[j];
            }
            #pragma unroll
            for (int i = 0; i < 4; ++i)
                #pragma unroll
                for (int j = 0; j < 4; ++j) {
                    int ii = ty * 4 + i, jj = tx * 4 + j;
                    S[ii][jj] = a4[i][j] * scale + b_rel[h * 4096 + ii * 64 + jj];
                }
        }
        __syncthreads();
        if (tid < 64) { // softmax rows
            float mx = -1e30f;
            for (int j = 0; j < 64; ++j) mx = fmaxf(mx, S[tid][j]);
            float sum = 0.f;
            for (int j = 0; j < 64; ++j) { float e = __expf(S[tid][j] - mx); S[tid][j] = e; sum += e; }
            float inv = 1.f / sum;
            for (int j = 0; j < 64; ++j) S[tid][j] *= inv;
        }
        __syncthreads();
        { // out = P @ v : 4 rows x 2 dims per thread
            const int i0 = ty * 4, d0 = tx * 2;
            float o[4][2] = {{0.f}};
            for (int j = 0; j < 64; ++j) {
                float v0 = vs[j][d0], v1 = vs[j][d0 + 1];
                #pragma unroll
                for (int i = 0; i < 4; ++i) {
                    float p = S[i0 + i][j];
                    o[i][0] += p * v0;
                    o[i][1] += p * v1;
                }
            }
            if (d0 < 30) {
                #pragma unroll
                for (int i = 0; i < 4; ++i) {
                    int r = i0 + i;
                    int l = ((wy << 3) + (r >> 3)) * IMG + (wx << 3) + (r & 7);
                    unsigned short* op = attn_out + (size_t)(b * LTOK + l) * CH + h * 30 + d0;
                    op[0] = f2b(o[i][0]);
                    op[1] = f2b(o[i][1]);
                }
            }
        }
        __syncthreads();
    }
}

// ---------------- depthwise 3x3 SAME conv (NHWC, bf16 act, fp32 weights) ----------------
template <int C, bool DO_GELU>
__global__ __launch_bounds__(256) void dwconv_kernel(
    const unsigned short* __restrict__ in, const float* __restrict__ w,
    unsigned short* __restrict__ out)
{
    int gid = blockIdx.x * 256 + threadIdx.x;
    if (gid >= BATCH * LTOK * C) return;
    int c = gid % C;
    int l = gid / C;
    int x = l & 255, y = (l >> 8) & 255;
    int bi = l >> 16;
    float s = 0.f;
    #pragma unroll
    for (int ky = 0; ky < 3; ++ky) {
        int yy = y + ky - 1;
        if (yy < 0 || yy > 255) continue;
        #pragma unroll
        for (int kx = 0; kx < 3; ++kx) {
            int xx = x + kx - 1;
            if (xx < 0 || xx > 255) continue;
            s += b2f(in[(size_t)((bi << 16) + (yy << 8) + xx) * C + c]) * w[c * 9 + ky * 3 + kx];
        }
    }
    if (DO_GELU) s = gelu_f(s);
    out[gid] = f2b(s);
}

// ---------------- sum-pool over L per (b,c) ----------------
__global__ __launch_bounds__(192) void pool_kernel(
    const unsigned short* __restrict__ cf, float* __restrict__ pooled)
{
    int t = threadIdx.x;
    if (t >= CH) return;
    int b = blockIdx.x >> 7;
    int chunk = blockIdx.x & 127;
    const unsigned short* base = cf + (size_t)(b * LTOK + chunk * 512) * CH + t;
    float s = 0.f;
    for (int i = 0; i < 512; ++i) s += b2f(base[(size_t)i * CH]);
    atomicAdd(&pooled[b * CH + t], s);
}

// ---------------- channel gate (fp32 weights) ----------------
__global__ __launch_bounds__(256) void cm_kernel(
    const float* __restrict__ pooled, const float* __restrict__ w1,
    const float* __restrict__ w2, float* __restrict__ cm)
{
    __shared__ float p[BATCH][CH];
    __shared__ float g1[BATCH][22];
    int t = threadIdx.x;
    for (int idx = t; idx < BATCH * CH; idx += 256)
        p[idx / CH][idx % CH] = pooled[idx] * (1.f / (float)LTOK);
    __syncthreads();
    if (t < BATCH * 22) {
        int b = t / 22, u = t % 22;
        float s = 0.f;
        for (int c = 0; c < CH; ++c) s += p[b][c] * w1[u * CH + c];
        g1[b][u] = gelu_f(s);
    }
    __syncthreads();
    for (int idx = t; idx < BATCH * CH; idx += 256) {
        int b = idx / CH, c = idx % CH;
        float s = 0.f;
        for (int u = 0; u < 22; ++u) s += g1[b][u] * w2[c * 22 + u];
        cm[idx] = 1.f / (1.f + __expf(-s));
    }
}

// ---------------- residual 1: x_mid = x(fp32) + attn_feat*cm + conv_feat -> bf16 ----------------
__global__ __launch_bounds__(256) void resid_kernel(
    const float* __restrict__ x, const unsigned short* __restrict__ attn_feat,
    const unsigned short* __restrict__ conv_feat, const float* __restrict__ cm,
    unsigned short* __restrict__ x_mid)
{
    int gid = blockIdx.x * 256 + threadIdx.x;
    if (gid >= BATCH * LTOK * CH) return;
    int c = gid % CH;
    int b = gid / (LTOK * CH);
    x_mid[gid] = f2b(x[gid] + b2f(attn_feat[gid]) * cm[b * CH + c] + b2f(conv_feat[gid]));
}

// ---------------- launch ----------------
extern "C" void kernel_launch(void* const* d_in, const int* in_sizes, int n_in,
                              void* d_out, int out_size, void* d_ws, size_t ws_size,
                              hipStream_t stream)
{
    const float* x       = (const float*)d_in[0];
    const float* w_qkv   = (const float*)d_in[1];
    const float* b_rel   = (const float*)d_in[2];
    const float* w_proj  = (const float*)d_in[3];
    const float* b_proj  = (const float*)d_in[4];
    const float* conv_dw = (const float*)d_in[5];
    const float* cg_w1   = (const float*)d_in[6];
    const float* cg_w2   = (const float*)d_in[7];
    const float* ffn_w1  = (const float*)d_in[8];
    const float* ffn_dw  = (const float*)d_in[9];
    const float* ffn_w2  = (const float*)d_in[10];
    const float* n1_g    = (const float*)d_in[11];
    const float* n1_b    = (const float*)d_in[12];
    const float* n2_g    = (const float*)d_in[13];
    const float* n2_b    = (const float*)d_in[14];

    // ---- workspace layout (bytes), peak ~236.5 MB ----
    // BLC2 = 131072*180*2 = 47,185,920
    char* ws = (char*)d_ws;
    unsigned short* n1        = (unsigned short*)(ws);                      // [0, 47.2MB)
    unsigned short* qkv       = (unsigned short*)(ws + 47185920);           // [47.2, 188.7MB)
    unsigned short* conv_feat = (unsigned short*)(ws + 188743680);          // [188.7, 235.9MB)
    unsigned short* attn_out  = (unsigned short*)(ws);                      // reuse n1 (dead after conv+qkv)
    unsigned short* attn_feat = (unsigned short*)(ws + 47185920);           // reuse qkv head (dead after attn)
    unsigned short* x_mid     = (unsigned short*)(ws + 94371840);           // reuse qkv mid
    unsigned short* n2        = (unsigned short*)(ws + 141557760);          // reuse qkv tail
    unsigned short* h         = (unsigned short*)(ws);                      // [0, 94.4MB)
    unsigned short* h_s       = (unsigned short*)(ws + 141557760);          // [141.6, 235.9MB)
    float*          pooled    = (float*)(ws + 235929600);                   // 1440 B
    float*          cmv       = (float*)(ws + 235931040);                   // 1440 B
    unsigned short* wbf       = (unsigned short*)(ws + 235932480);          // 518,400 B bf16 weights
    unsigned short* wqkv_b = wbf;              // 97200
    unsigned short* wproj_b = wbf + 97200;     // 32400
    unsigned short* wffn1_b = wbf + 129600;    // 64800
    unsigned short* wffn2_b = wbf + 194400;    // 64800
    float* out = (float*)d_out;

    hipMemsetAsync(pooled, 0, 2880, stream);

    // 0. convert GEMM weights fp32 -> bf16
    convw_kernel<<<1013, 256, 0, stream>>>(w_qkv, w_proj, ffn_w1, ffn_w2, wbf);
    // 1. LN1: x(fp32) -> n1(bf16)
    ln_kernel<float><<<BL / 4, 256, 0, stream>>>(x, n1_g, n1_b, n1);
    // 2. qkv = n1 @ w_qkv^T  (N=540, K=180)
    gemm_kernel<0, false, false, unsigned short><<<dim3(BL / 64, 9), 256, 0, stream>>>(
        n1, CH, wqkv_b, nullptr, nullptr, 0, qkv, 540, 540, CH);
    // 3. conv branch: gelu(dwconv3x3(n1)) -> conv_feat
    dwconv_kernel<CH, true><<<(BATCH * LTOK * CH) / 256, 256, 0, stream>>>(n1, conv_dw, conv_feat);
    // 4. pooled = sum_L conv_feat
    pool_kernel<<<BATCH * 128, 192, 0, stream>>>(conv_feat, pooled);
    // 5. cm
    cm_kernel<<<1, 256, 0, stream>>>(pooled, cg_w1, cg_w2, cmv);
    // 6. window attention -> attn_out (over n1's region)
    attn_kernel<<<2048, 256, 0, stream>>>(qkv, b_rel, attn_out);
    // 7. attn_feat = attn_out @ w_proj^T + b_proj  (N=180, K=180)
    gemm_kernel<0, true, false, unsigned short><<<dim3(BL / 64, 3), 256, 0, stream>>>(
        attn_out, CH, wproj_b, b_proj, nullptr, 0, attn_feat, CH, CH, CH);
    // 8. x_mid = x + attn_feat*cm + conv_feat  (bf16)
    resid_kernel<<<(BATCH * LTOK * CH) / 256, 256, 0, stream>>>(x, attn_feat, conv_feat, cmv, x_mid);
    // 9. LN2: x_mid(bf16) -> n2(bf16)
    ln_kernel<unsigned short><<<BL / 4, 256, 0, stream>>>(x_mid, n2_g, n2_b, n2);
    // 10. h = gelu(n2 @ ffn_w1^T)  (N=360, K=180)
    gemm_kernel<1, false, false, unsigned short><<<dim3(BL / 64, 6), 256, 0, stream>>>(
        n2, CH, wffn1_b, nullptr, nullptr, 0, h, HDF, HDF, CH);
    // 11. h_s = dwconv3x3(h)  (C=360, no act)
    dwconv_kernel<HDF, false><<<(BATCH * LTOK * HDF) / 256, 256, 0, stream>>>(h, ffn_dw, h_s);
    // 12. out(fp32) = x_mid + h_s @ ffn_w2^T  (N=180, K=360)
    gemm_kernel<0, false, true, float><<<dim3(BL / 64, 3), 256, 0, stream>>>(
        h_s, HDF, wffn2_b, nullptr, x_mid, CH, out, CH, CH, HDF);
}

// Round 4
// 1111.355 us; speedup vs baseline: 1.3995x; 1.3995x over previous
//
#include <hip/hip_runtime.h>
#include <hip/hip_bf16.h>
#include <math.h>

// ---------------- constants (problem is fixed-shape) ----------------
// B=2, H=W=256, L=65536, C=180, NH=6, hd=30, WS=8, hd_ffn=360
// I/O dtype: fp32 (per reference). Internals: bf16 (MFMA), fp32 accum.
#define BATCH 2
#define IMG 256
#define LTOK 65536
#define CH 180
#define BL (BATCH * LTOK)            // 131072 tokens
#define HDF 360

using frag_ab = __attribute__((ext_vector_type(8))) short;   // 8 bf16 in 4 VGPRs
using frag_cd = __attribute__((ext_vector_type(4))) float;   // 4 f32 acc

__device__ __forceinline__ float b2f(unsigned short u) {
    union { unsigned int i; float f; } v; v.i = ((unsigned int)u) << 16; return v.f;
}
__device__ __forceinline__ float blo(unsigned int u) {
    union { unsigned int i; float f; } v; v.i = u << 16; return v.f;
}
__device__ __forceinline__ float bhi(unsigned int u) {
    union { unsigned int i; float f; } v; v.i = u & 0xffff0000u; return v.f;
}
__device__ __forceinline__ unsigned short f2b(float f) {
    union { float f; unsigned int i; } v; v.f = f;
    unsigned int x = v.i;
    unsigned int r = (x + 0x7fffu + ((x >> 16) & 1u)) >> 16;   // RNE
    return (unsigned short)r;
}
__device__ __forceinline__ float gelu_f(float x) {
    return 0.5f * x * (1.0f + erff(x * 0.70710678118654752f));
}

// ---------------- one-shot weight prep ----------------
// wbf: w_qkv 97200 | w_proj 32400 | ffn_w1 64800 | ffn_w2 64800 = 259200 bf16
// wT1: conv_dw transposed [9][180] fp32 (6480) ; wT2: ffn_dw [9][360] fp32 (12960)
__global__ __launch_bounds__(256) void convw_kernel(
    const float* __restrict__ a, const float* __restrict__ b,
    const float* __restrict__ c, const float* __restrict__ d,
    const float* __restrict__ cdw, const float* __restrict__ fdw,
    unsigned short* __restrict__ wbf, float* __restrict__ wT1, float* __restrict__ wT2)
{
    int g = blockIdx.x * 256 + threadIdx.x;
    if (g < 259200) {
        float v;
        if      (g < 97200)  v = a[g];
        else if (g < 129600) v = b[g - 97200];
        else if (g < 194400) v = c[g - 129600];
        else                 v = d[g - 194400];
        wbf[g] = f2b(v);
    } else if (g < 265680) {
        int i = g - 259200;               // tap-major [9][180]
        int tap = i / 180, ch = i % 180;
        wT1[i] = cdw[ch * 9 + tap];
    } else if (g < 278640) {
        int i = g - 265680;               // [9][360]
        int tap = i / 360, ch = i % 360;
        wT2[i] = fdw[ch * 9 + tap];
    }
}

// ---------------- LayerNorm: one wave per token, vectorized (45 active lanes) ----------------
__device__ __forceinline__ void ld4(const float* p, float v[4]) {
    float4 t = *(const float4*)p; v[0]=t.x; v[1]=t.y; v[2]=t.z; v[3]=t.w;
}
__device__ __forceinline__ void ld4(const unsigned short* p, float v[4]) {
    ushort4 t = *(const ushort4*)p; v[0]=b2f(t.x); v[1]=b2f(t.y); v[2]=b2f(t.z); v[3]=b2f(t.w);
}

template <typename TIN>
__global__ __launch_bounds__(256) void ln_kernel(
    const TIN* __restrict__ x, const float* __restrict__ g,
    const float* __restrict__ bta, unsigned short* __restrict__ out)
{
    int wave = threadIdx.x >> 6, lane = threadIdx.x & 63;
    int tok = blockIdx.x * 4 + wave;
    const bool act = lane < 45;                 // 45*4 = 180 channels
    float v[4] = {0.f, 0.f, 0.f, 0.f};
    const TIN* row = x + (size_t)tok * CH;
    if (act) ld4(row + lane * 4, v);
    float s  = v[0] + v[1] + v[2] + v[3];
    float sq = v[0]*v[0] + v[1]*v[1] + v[2]*v[2] + v[3]*v[3];
    #pragma unroll
    for (int off = 32; off > 0; off >>= 1) {
        s  += __shfl_xor(s, off);
        sq += __shfl_xor(sq, off);
    }
    float mean = s * (1.f / CH);
    float var  = sq * (1.f / CH) - mean * mean;
    float rstd = rsqrtf(var + 1e-5f);
    if (act) {
        float4 gg = *(const float4*)&g[lane * 4];
        float4 bb = *(const float4*)&bta[lane * 4];
        unsigned int o0 = (unsigned int)f2b((v[0]-mean)*rstd*gg.x + bb.x)
                        | ((unsigned int)f2b((v[1]-mean)*rstd*gg.y + bb.y) << 16);
        unsigned int o1 = (unsigned int)f2b((v[2]-mean)*rstd*gg.z + bb.z)
                        | ((unsigned int)f2b((v[3]-mean)*rstd*gg.w + bb.w) << 16);
        *(uint2*)(out + (size_t)tok * CH + lane * 4) = make_uint2(o0, o1);
    }
}

// ---------------- generic MFMA GEMM (unchanged from round 3) ----------------
__device__ __forceinline__ void stv(float* p, float v) { *p = v; }
__device__ __forceinline__ void stv(unsigned short* p, float v) { *p = f2b(v); }

template <int ACT, bool HAS_BIAS, bool HAS_RES, typename TOUT>
__global__ __launch_bounds__(256) void gemm_kernel(
    const unsigned short* __restrict__ X, int ldx,
    const unsigned short* __restrict__ Wt,
    const float* __restrict__ bias,
    const unsigned short* __restrict__ res, int ldr,
    TOUT* __restrict__ Y, int ldy,
    int N, int K)
{
    __shared__ unsigned short Xs[64][40];
    __shared__ unsigned short Ws[64][40];
    const int tid = threadIdx.x;
    const int wave = tid >> 6;
    const int lane = tid & 63;
    const int l16 = lane & 15;
    const int q = lane >> 4;
    const int m0 = blockIdx.x * 64;
    const int n0 = blockIdx.y * 64;
    const int lr = tid >> 2;
    const int lk = (tid & 3) << 3;

    frag_cd acc[4];
    #pragma unroll
    for (int i = 0; i < 4; ++i) acc[i] = (frag_cd){0.f, 0.f, 0.f, 0.f};

    for (int k0 = 0; k0 < K; k0 += 32) {
        const bool kfull = (k0 + 32 <= K);
        {
            const unsigned short* p = X + (size_t)(m0 + lr) * ldx + (k0 + lk);
            if (kfull) {
                *(uint2*)&Xs[lr][lk]     = *(const uint2*)p;
                *(uint2*)&Xs[lr][lk + 4] = *(const uint2*)(p + 4);
            } else {
                #pragma unroll
                for (int j = 0; j < 8; ++j)
                    Xs[lr][lk + j] = (k0 + lk + j < K) ? p[j] : (unsigned short)0;
            }
        }
        {
            const int n = n0 + lr;
            const unsigned short* p = Wt + (size_t)n * K + (k0 + lk);
            if (n < N && kfull) {
                *(uint2*)&Ws[lr][lk]     = *(const uint2*)p;
                *(uint2*)&Ws[lr][lk + 4] = *(const uint2*)(p + 4);
            } else {
                #pragma unroll
                for (int j = 0; j < 8; ++j)
                    Ws[lr][lk + j] = (n < N && (k0 + lk + j) < K) ? p[j] : (unsigned short)0;
            }
        }
        __syncthreads();
        frag_ab bfr = *(const frag_ab*)&Ws[wave * 16 + l16][q * 8];
        #pragma unroll
        for (int mb = 0; mb < 4; ++mb) {
            frag_ab afr = *(const frag_ab*)&Xs[mb * 16 + l16][q * 8];
            acc[mb] = __builtin_amdgcn_mfma_f32_16x16x32_bf16(afr, bfr, acc[mb], 0, 0, 0);
        }
        __syncthreads();
    }
    const int col = n0 + wave * 16 + l16;
    if (col < N) {
        float bv = 0.f;
        if (HAS_BIAS) bv = bias[col];
        #pragma unroll
        for (int mb = 0; mb < 4; ++mb) {
            #pragma unroll
            for (int r = 0; r < 4; ++r) {
                int row = m0 + mb * 16 + q * 4 + r;
                float v = acc[mb][r] + bv;
                if (ACT == 1) v = gelu_f(v);
                if (HAS_RES) v += b2f(res[(size_t)row * ldr + col]);
                stv(&Y[(size_t)row * ldy + col], v);
            }
        }
    }
}

// ---------------- window attention (unchanged) ----------------
__global__ __launch_bounds__(256) void attn_kernel(
    const unsigned short* __restrict__ qkv,
    const float* __restrict__ b_rel,
    unsigned short* __restrict__ attn_out)
{
    __shared__ float qs[64][33], ks[64][33], vs[64][33];
    __shared__ float S[64][65];
    const int tid = threadIdx.x;
    const int wid = blockIdx.x;
    const int b = wid >> 10;
    const int wy = (wid & 1023) >> 5;
    const int wx = wid & 31;
    const float scale = 0.18257418583505536f;
    const int ty = tid >> 4, tx = tid & 15;

    for (int h = 0; h < 6; ++h) {
        for (int idx = tid; idx < 64 * 32; idx += 256) {
            int r = idx >> 5, d = idx & 31;
            float qv = 0.f, kv = 0.f, vv = 0.f;
            if (d < 30) {
                int l = ((wy << 3) + (r >> 3)) * IMG + (wx << 3) + (r & 7);
                const unsigned short* rowp = qkv + (size_t)(b * LTOK + l) * 540 + h * 30 + d;
                qv = b2f(rowp[0]); kv = b2f(rowp[180]); vv = b2f(rowp[360]);
            }
            qs[r][d] = qv; ks[r][d] = kv; vs[r][d] = vv;
        }
        __syncthreads();
        {
            float a4[4][4] = {{0.f}};
            for (int d = 0; d < 30; ++d) {
                float qv[4], kv[4];
                #pragma unroll
                for (int i = 0; i < 4; ++i) qv[i] = qs[ty * 4 + i][d];
                #pragma unroll
                for (int j = 0; j < 4; ++j) kv[j] = ks[tx * 4 + j][d];
                #pragma unroll
                for (int i = 0; i < 4; ++i)
                    #pragma unroll
                    for (int j = 0; j < 4; ++j) a4[i][j] += qv[i] * kv[j];
            }
            #pragma unroll
            for (int i = 0; i < 4; ++i)
                #pragma unroll
                for (int j = 0; j < 4; ++j) {
                    int ii = ty * 4 + i, jj = tx * 4 + j;
                    S[ii][jj] = a4[i][j] * scale + b_rel[h * 4096 + ii * 64 + jj];
                }
        }
        __syncthreads();
        if (tid < 64) {
            float mx = -1e30f;
            for (int j = 0; j < 64; ++j) mx = fmaxf(mx, S[tid][j]);
            float sum = 0.f;
            for (int j = 0; j < 64; ++j) { float e = __expf(S[tid][j] - mx); S[tid][j] = e; sum += e; }
            float inv = 1.f / sum;
            for (int j = 0; j < 64; ++j) S[tid][j] *= inv;
        }
        __syncthreads();
        {
            const int i0 = ty * 4, d0 = tx * 2;
            float o[4][2] = {{0.f}};
            for (int j = 0; j < 64; ++j) {
                float v0 = vs[j][d0], v1 = vs[j][d0 + 1];
                #pragma unroll
                for (int i = 0; i < 4; ++i) {
                    float p = S[i0 + i][j];
                    o[i][0] += p * v0;
                    o[i][1] += p * v1;
                }
            }
            if (d0 < 30) {
                #pragma unroll
                for (int i = 0; i < 4; ++i) {
                    int r = i0 + i;
                    int l = ((wy << 3) + (r >> 3)) * IMG + (wx << 3) + (r & 7);
                    unsigned short* op = attn_out + (size_t)(b * LTOK + l) * CH + h * 30 + d0;
                    op[0] = f2b(o[i][0]);
                    op[1] = f2b(o[i][1]);
                }
            }
        }
        __syncthreads();
    }
}

// ---------------- depthwise 3x3 SAME conv, vectorized column-walk ----------------
// thread = (batch, x, 8-channel group), walks TY=8 output rows; ring of 3 input
// rows in packed-bf16 regs; fp32 weights from transposed wT[tap][C] in regs.
template <int C, bool DO_GELU>
__global__ __launch_bounds__(256) void dwconv_kernel(
    const unsigned short* __restrict__ in, const float* __restrict__ wT,
    unsigned short* __restrict__ out)
{
    constexpr int NG = (C + 7) / 8;      // 23 (C=180, last group 4 valid) / 45 (C=360)
    constexpr int TY = 8;
    int gid = blockIdx.x * 256 + threadIdx.x;
    int cg = gid % NG;
    int t  = gid / NG;
    int x  = t % IMG;
    int t2 = t / IMG;
    int yb = t2 & 31;                    // IMG/TY = 32
    int bi = t2 >> 5;
    if (bi >= BATCH) return;
    const int c0 = cg * 8;
    const int y0 = yb * TY;

    float w9[9][8];
    #pragma unroll
    for (int tp = 0; tp < 9; ++tp) {
        float4 wa = *(const float4*)&wT[tp * C + c0];
        float4 wb = *(const float4*)&wT[tp * C + c0 + 4];
        w9[tp][0]=wa.x; w9[tp][1]=wa.y; w9[tp][2]=wa.z; w9[tp][3]=wa.w;
        w9[tp][4]=wb.x; w9[tp][5]=wb.y; w9[tp][6]=wb.z; w9[tp][7]=wb.w;
    }

    unsigned int rr[3][3][4];            // [ring][col][4 packed uints = 8 bf16]

    auto load_row = [&](int y, unsigned int dst[3][4]) {
        if ((unsigned)y >= (unsigned)IMG) {
            #pragma unroll
            for (int cc = 0; cc < 3; ++cc)
                #pragma unroll
                for (int k = 0; k < 4; ++k) dst[cc][k] = 0u;
            return;
        }
        size_t base = ((size_t)((bi << 16) + (y << 8) + x)) * C + c0;
        #pragma unroll
        for (int cc = 0; cc < 3; ++cc) {
            int xx = x + cc - 1;
            if ((unsigned)xx >= (unsigned)IMG) {
                dst[cc][0] = dst[cc][1] = dst[cc][2] = dst[cc][3] = 0u;
                continue;
            }
            const unsigned short* p = in + base + (ptrdiff_t)(cc - 1) * C;
            uint2 u0 = *(const uint2*)p;
            uint2 u1 = *(const uint2*)(p + 4);
            dst[cc][0] = u0.x; dst[cc][1] = u0.y; dst[cc][2] = u1.x; dst[cc][3] = u1.y;
        }
    };

    load_row(y0 - 1, rr[0]);
    load_row(y0,     rr[1]);

    #pragma unroll
    for (int dy = 0; dy < TY; ++dy) {
        load_row(y0 + dy + 1, rr[(dy + 2) % 3]);
        float acc[8];
        #pragma unroll
        for (int j = 0; j < 8; ++j) acc[j] = 0.f;
        #pragma unroll
        for (int ky = 0; ky < 3; ++ky) {
            unsigned int (*row)[4] = rr[(dy + ky) % 3];
            #pragma unroll
            for (int kx = 0; kx < 3; ++kx) {
                const float* wp = w9[ky * 3 + kx];
                const unsigned int* u = row[kx];
                acc[0] += blo(u[0]) * wp[0];
                acc[1] += bhi(u[0]) * wp[1];
                acc[2] += blo(u[1]) * wp[2];
                acc[3] += bhi(u[1]) * wp[3];
                acc[4] += blo(u[2]) * wp[4];
                acc[5] += bhi(u[2]) * wp[5];
                acc[6] += blo(u[3]) * wp[6];
                acc[7] += bhi(u[3]) * wp[7];
            }
        }
        if (DO_GELU) {
            #pragma unroll
            for (int j = 0; j < 8; ++j) acc[j] = gelu_f(acc[j]);
        }
        size_t ob = ((size_t)((bi << 16) + ((y0 + dy) << 8) + x)) * C + c0;
        unsigned int o0 = (unsigned int)f2b(acc[0]) | ((unsigned int)f2b(acc[1]) << 16);
        unsigned int o1 = (unsigned int)f2b(acc[2]) | ((unsigned int)f2b(acc[3]) << 16);
        *(uint2*)(out + ob) = make_uint2(o0, o1);
        if (c0 + 8 <= C) {
            unsigned int o2 = (unsigned int)f2b(acc[4]) | ((unsigned int)f2b(acc[5]) << 16);
            unsigned int o3 = (unsigned int)f2b(acc[6]) | ((unsigned int)f2b(acc[7]) << 16);
            *(uint2*)(out + ob + 4) = make_uint2(o2, o3);
        }
    }
}

// ---------------- sum-pool over L per (b,c), ushort4 ----------------
__global__ __launch_bounds__(64) void pool_kernel(
    const unsigned short* __restrict__ cf, float* __restrict__ pooled)
{
    int t = threadIdx.x;
    if (t >= 45) return;
    int b = blockIdx.x >> 7;
    int chunk = blockIdx.x & 127;
    const unsigned short* base = cf + (size_t)(b * LTOK + chunk * 512) * CH + t * 4;
    float s0 = 0.f, s1 = 0.f, s2 = 0.f, s3 = 0.f;
    for (int i = 0; i < 512; ++i) {
        ushort4 v = *(const ushort4*)(base + (size_t)i * CH);
        s0 += b2f(v.x); s1 += b2f(v.y); s2 += b2f(v.z); s3 += b2f(v.w);
    }
    atomicAdd(&pooled[b * CH + t * 4 + 0], s0);
    atomicAdd(&pooled[b * CH + t * 4 + 1], s1);
    atomicAdd(&pooled[b * CH + t * 4 + 2], s2);
    atomicAdd(&pooled[b * CH + t * 4 + 3], s3);
}

// ---------------- channel gate (unchanged) ----------------
__global__ __launch_bounds__(256) void cm_kernel(
    const float* __restrict__ pooled, const float* __restrict__ w1,
    const float* __restrict__ w2, float* __restrict__ cm)
{
    __shared__ float p[BATCH][CH];
    __shared__ float g1[BATCH][22];
    int t = threadIdx.x;
    for (int idx = t; idx < BATCH * CH; idx += 256)
        p[idx / CH][idx % CH] = pooled[idx] * (1.f / (float)LTOK);
    __syncthreads();
    if (t < BATCH * 22) {
        int b = t / 22, u = t % 22;
        float s = 0.f;
        for (int c = 0; c < CH; ++c) s += p[b][c] * w1[u * CH + c];
        g1[b][u] = gelu_f(s);
    }
    __syncthreads();
    for (int idx = t; idx < BATCH * CH; idx += 256) {
        int b = idx / CH, c = idx % CH;
        float s = 0.f;
        for (int u = 0; u < 22; ++u) s += g1[b][u] * w2[c * 22 + u];
        cm[idx] = 1.f / (1.f + __expf(-s));
    }
}

// ---------------- residual 1, 4 channels/thread ----------------
__global__ __launch_bounds__(256) void resid_kernel(
    const float* __restrict__ x, const unsigned short* __restrict__ attn_feat,
    const unsigned short* __restrict__ conv_feat, const float* __restrict__ cm,
    unsigned short* __restrict__ x_mid)
{
    int gid = blockIdx.x * 256 + threadIdx.x;     // BL*CH/4 threads
    int c4 = gid % 45;
    int b = gid / (LTOK * 45);
    float4 xv = ((const float4*)x)[gid];
    ushort4 a = ((const ushort4*)attn_feat)[gid];
    ushort4 c = ((const ushort4*)conv_feat)[gid];
    float4 m = *(const float4*)&cm[b * CH + c4 * 4];
    unsigned int o0 = (unsigned int)f2b(xv.x + b2f(a.x) * m.x + b2f(c.x))
                    | ((unsigned int)f2b(xv.y + b2f(a.y) * m.y + b2f(c.y)) << 16);
    unsigned int o1 = (unsigned int)f2b(xv.z + b2f(a.z) * m.z + b2f(c.z))
                    | ((unsigned int)f2b(xv.w + b2f(a.w) * m.w + b2f(c.w)) << 16);
    ((uint2*)x_mid)[gid] = make_uint2(o0, o1);
}

// ---------------- launch ----------------
extern "C" void kernel_launch(void* const* d_in, const int* in_sizes, int n_in,
                              void* d_out, int out_size, void* d_ws, size_t ws_size,
                              hipStream_t stream)
{
    const float* x       = (const float*)d_in[0];
    const float* w_qkv   = (const float*)d_in[1];
    const float* b_rel   = (const float*)d_in[2];
    const float* w_proj  = (const float*)d_in[3];
    const float* b_proj  = (const float*)d_in[4];
    const float* conv_dw = (const float*)d_in[5];
    const float* cg_w1   = (const float*)d_in[6];
    const float* cg_w2   = (const float*)d_in[7];
    const float* ffn_w1  = (const float*)d_in[8];
    const float* ffn_dw  = (const float*)d_in[9];
    const float* ffn_w2  = (const float*)d_in[10];
    const float* n1_g    = (const float*)d_in[11];
    const float* n1_b    = (const float*)d_in[12];
    const float* n2_g    = (const float*)d_in[13];
    const float* n2_b    = (const float*)d_in[14];

    // ---- workspace layout (bytes), peak ~225.6 MiB ----
    // BLC2 = 131072*180*2 = 47,185,920
    char* ws = (char*)d_ws;
    unsigned short* n1        = (unsigned short*)(ws);                      // [0, 47.2MB)
    unsigned short* qkv       = (unsigned short*)(ws + 47185920);           // [47.2, 188.7MB)
    unsigned short* conv_feat = (unsigned short*)(ws + 188743680);          // [188.7, 235.9MB)
    unsigned short* attn_out  = (unsigned short*)(ws);                      // reuse n1
    unsigned short* attn_feat = (unsigned short*)(ws + 47185920);           // reuse qkv head
    unsigned short* x_mid     = (unsigned short*)(ws + 94371840);           // reuse qkv mid
    unsigned short* n2        = (unsigned short*)(ws + 141557760);          // reuse qkv tail
    unsigned short* h         = (unsigned short*)(ws);                      // [0, 94.4MB)
    unsigned short* h_s       = (unsigned short*)(ws + 141557760);          // [141.6, 235.9MB)
    float*          pooled    = (float*)(ws + 235929600);                   // 1440 B
    float*          cmv       = (float*)(ws + 235931040);                   // 1440 B
    unsigned short* wbf       = (unsigned short*)(ws + 235932480);          // 518,400 B
    float*          wT1       = (float*)(ws + 236450880);                   // 25,920 B
    float*          wT2       = (float*)(ws + 236476800);                   // 51,840 B -> end 236,528,640
    unsigned short* wqkv_b  = wbf;
    unsigned short* wproj_b = wbf + 97200;
    unsigned short* wffn1_b = wbf + 129600;
    unsigned short* wffn2_b = wbf + 194400;
    float* out = (float*)d_out;

    hipMemsetAsync(pooled, 0, 2880, stream);

    // 0. weight prep (bf16 GEMM weights + transposed conv weights)
    convw_kernel<<<1089, 256, 0, stream>>>(w_qkv, w_proj, ffn_w1, ffn_w2,
                                           conv_dw, ffn_dw, wbf, wT1, wT2);
    // 1. LN1: x(fp32) -> n1(bf16)
    ln_kernel<float><<<BL / 4, 256, 0, stream>>>(x, n1_g, n1_b, n1);
    // 2. qkv = n1 @ w_qkv^T  (N=540, K=180)
    gemm_kernel<0, false, false, unsigned short><<<dim3(BL / 64, 9), 256, 0, stream>>>(
        n1, CH, wqkv_b, nullptr, nullptr, 0, qkv, 540, 540, CH);
    // 3. conv branch: gelu(dwconv3x3(n1)) -> conv_feat
    dwconv_kernel<CH, true><<<1472, 256, 0, stream>>>(n1, wT1, conv_feat);
    // 4. pooled = sum_L conv_feat
    pool_kernel<<<BATCH * 128, 64, 0, stream>>>(conv_feat, pooled);
    // 5. cm
    cm_kernel<<<1, 256, 0, stream>>>(pooled, cg_w1, cg_w2, cmv);
    // 6. window attention -> attn_out
    attn_kernel<<<2048, 256, 0, stream>>>(qkv, b_rel, attn_out);
    // 7. attn_feat = attn_out @ w_proj^T + b_proj  (N=180, K=180)
    gemm_kernel<0, true, false, unsigned short><<<dim3(BL / 64, 3), 256, 0, stream>>>(
        attn_out, CH, wproj_b, b_proj, nullptr, 0, attn_feat, CH, CH, CH);
    // 8. x_mid = x + attn_feat*cm + conv_feat  (bf16)
    resid_kernel<<<(BL * CH / 4) / 256, 256, 0, stream>>>(x, attn_feat, conv_feat, cmv, x_mid);
    // 9. LN2: x_mid(bf16) -> n2(bf16)
    ln_kernel<unsigned short><<<BL / 4, 256, 0, stream>>>(x_mid, n2_g, n2_b, n2);
    // 10. h = gelu(n2 @ ffn_w1^T)  (N=360, K=180)
    gemm_kernel<1, false, false, unsigned short><<<dim3(BL / 64, 6), 256, 0, stream>>>(
        n2, CH, wffn1_b, nullptr, nullptr, 0, h, HDF, HDF, CH);
    // 11. h_s = dwconv3x3(h)  (C=360, no act)
    dwconv_kernel<HDF, false><<<2880, 256, 0, stream>>>(h, wT2, h_s);
    // 12. out(fp32) = x_mid + h_s @ ffn_w2^T  (N=180, K=360)
    gemm_kernel<0, false, true, float><<<dim3(BL / 64, 3), 256, 0, stream>>>(
        h_s, HDF, wffn2_b, nullptr, x_mid, CH, out, CH, CH, HDF);
}

// Round 5
// 1063.586 us; speedup vs baseline: 1.4624x; 1.0449x over previous
//
#include <hip/hip_runtime.h>
#include <hip/hip_bf16.h>
#include <math.h>

// ---------------- constants (problem is fixed-shape) ----------------
// B=2, H=W=256, L=65536, C=180, NH=6, hd=30, WS=8, hd_ffn=360
// I/O dtype: fp32 (per reference). Internals: bf16 (MFMA), fp32 accum.
#define BATCH 2
#define IMG 256
#define LTOK 65536
#define CH 180
#define BL (BATCH * LTOK)            // 131072 tokens
#define HDF 360

using frag_ab = __attribute__((ext_vector_type(8))) short;   // 8 bf16 in 4 VGPRs
using frag_cd = __attribute__((ext_vector_type(4))) float;   // 4 f32 acc

__device__ __forceinline__ float b2f(unsigned short u) {
    union { unsigned int i; float f; } v; v.i = ((unsigned int)u) << 16; return v.f;
}
__device__ __forceinline__ float blo(unsigned int u) {
    union { unsigned int i; float f; } v; v.i = u << 16; return v.f;
}
__device__ __forceinline__ float bhi(unsigned int u) {
    union { unsigned int i; float f; } v; v.i = u & 0xffff0000u; return v.f;
}
__device__ __forceinline__ unsigned short f2b(float f) {
    union { float f; unsigned int i; } v; v.f = f;
    unsigned int x = v.i;
    unsigned int r = (x + 0x7fffu + ((x >> 16) & 1u)) >> 16;   // RNE
    return (unsigned short)r;
}
__device__ __forceinline__ float gelu_f(float x) {
    return 0.5f * x * (1.0f + erff(x * 0.70710678118654752f));
}

// row-index permutations for window attention, folded into GEMM epilogues.
// PERM=1: token-order row -> window-order position. PERM=2: inverse.
template <int PERM>
__device__ __forceinline__ int perm_row(int row) {
    if (PERM == 1) {
        int b = row >> 16, l = row & 65535;
        int y = l >> 8, x = l & 255;
        return (b << 16) + ((((y >> 3) << 5) + (x >> 3)) << 6) + ((y & 7) << 3) + (x & 7);
    } else if (PERM == 2) {
        int b = row >> 16, wv = row & 65535;
        int wid = wv >> 6, t = wv & 63;
        int wy = wid >> 5, wx = wid & 31;
        return (b << 16) + ((((wy << 3) + (t >> 3))) << 8) + (wx << 3) + (t & 7);
    }
    return row;
}

// ---------------- one-shot weight prep ----------------
__global__ __launch_bounds__(256) void convw_kernel(
    const float* __restrict__ a, const float* __restrict__ b,
    const float* __restrict__ c, const float* __restrict__ d,
    const float* __restrict__ cdw, const float* __restrict__ fdw,
    unsigned short* __restrict__ wbf, float* __restrict__ wT1, float* __restrict__ wT2)
{
    int g = blockIdx.x * 256 + threadIdx.x;
    if (g < 259200) {
        float v;
        if      (g < 97200)  v = a[g];
        else if (g < 129600) v = b[g - 97200];
        else if (g < 194400) v = c[g - 129600];
        else                 v = d[g - 194400];
        wbf[g] = f2b(v);
    } else if (g < 265680) {
        int i = g - 259200;               // tap-major [9][180]
        int tap = i / 180, ch = i % 180;
        wT1[i] = cdw[ch * 9 + tap];
    } else if (g < 278640) {
        int i = g - 265680;               // [9][360]
        int tap = i / 360, ch = i % 360;
        wT2[i] = fdw[ch * 9 + tap];
    }
}

// ---------------- LayerNorm: one wave per token, vectorized (45 active lanes) ----------------
__device__ __forceinline__ void ld4(const float* p, float v[4]) {
    float4 t = *(const float4*)p; v[0]=t.x; v[1]=t.y; v[2]=t.z; v[3]=t.w;
}
__device__ __forceinline__ void ld4(const unsigned short* p, float v[4]) {
    ushort4 t = *(const ushort4*)p; v[0]=b2f(t.x); v[1]=b2f(t.y); v[2]=b2f(t.z); v[3]=b2f(t.w);
}

template <typename TIN>
__global__ __launch_bounds__(256) void ln_kernel(
    const TIN* __restrict__ x, const float* __restrict__ g,
    const float* __restrict__ bta, unsigned short* __restrict__ out)
{
    int wave = threadIdx.x >> 6, lane = threadIdx.x & 63;
    int tok = blockIdx.x * 4 + wave;
    const bool act = lane < 45;                 // 45*4 = 180 channels
    float v[4] = {0.f, 0.f, 0.f, 0.f};
    const TIN* row = x + (size_t)tok * CH;
    if (act) ld4(row + lane * 4, v);
    float s  = v[0] + v[1] + v[2] + v[3];
    float sq = v[0]*v[0] + v[1]*v[1] + v[2]*v[2] + v[3]*v[3];
    #pragma unroll
    for (int off = 32; off > 0; off >>= 1) {
        s  += __shfl_xor(s, off);
        sq += __shfl_xor(sq, off);
    }
    float mean = s * (1.f / CH);
    float var  = sq * (1.f / CH) - mean * mean;
    float rstd = rsqrtf(var + 1e-5f);
    if (act) {
        float4 gg = *(const float4*)&g[lane * 4];
        float4 bb = *(const float4*)&bta[lane * 4];
        unsigned int o0 = (unsigned int)f2b((v[0]-mean)*rstd*gg.x + bb.x)
                        | ((unsigned int)f2b((v[1]-mean)*rstd*gg.y + bb.y) << 16);
        unsigned int o1 = (unsigned int)f2b((v[2]-mean)*rstd*gg.z + bb.z)
                        | ((unsigned int)f2b((v[3]-mean)*rstd*gg.w + bb.w) << 16);
        *(uint2*)(out + (size_t)tok * CH + lane * 4) = make_uint2(o0, o1);
    }
}

// ---------------- generic MFMA GEMM (+ optional row-perm epilogue) ----------------
__device__ __forceinline__ void stv(float* p, float v) { *p = v; }
__device__ __forceinline__ void stv(unsigned short* p, float v) { *p = f2b(v); }

template <int ACT, bool HAS_BIAS, bool HAS_RES, int PERM, typename TOUT>
__global__ __launch_bounds__(256) void gemm_kernel(
    const unsigned short* __restrict__ X, int ldx,
    const unsigned short* __restrict__ Wt,
    const float* __restrict__ bias,
    const unsigned short* __restrict__ res, int ldr,
    TOUT* __restrict__ Y, int ldy,
    int N, int K)
{
    __shared__ unsigned short Xs[64][40];
    __shared__ unsigned short Ws[64][40];
    const int tid = threadIdx.x;
    const int wave = tid >> 6;
    const int lane = tid & 63;
    const int l16 = lane & 15;
    const int q = lane >> 4;
    const int m0 = blockIdx.x * 64;
    const int n0 = blockIdx.y * 64;
    const int lr = tid >> 2;
    const int lk = (tid & 3) << 3;

    frag_cd acc[4];
    #pragma unroll
    for (int i = 0; i < 4; ++i) acc[i] = (frag_cd){0.f, 0.f, 0.f, 0.f};

    for (int k0 = 0; k0 < K; k0 += 32) {
        const bool kfull = (k0 + 32 <= K);
        {
            const unsigned short* p = X + (size_t)(m0 + lr) * ldx + (k0 + lk);
            if (kfull) {
                *(uint2*)&Xs[lr][lk]     = *(const uint2*)p;
                *(uint2*)&Xs[lr][lk + 4] = *(const uint2*)(p + 4);
            } else {
                #pragma unroll
                for (int j = 0; j < 8; ++j)
                    Xs[lr][lk + j] = (k0 + lk + j < K) ? p[j] : (unsigned short)0;
            }
        }
        {
            const int n = n0 + lr;
            const unsigned short* p = Wt + (size_t)n * K + (k0 + lk);
            if (n < N && kfull) {
                *(uint2*)&Ws[lr][lk]     = *(const uint2*)p;
                *(uint2*)&Ws[lr][lk + 4] = *(const uint2*)(p + 4);
            } else {
                #pragma unroll
                for (int j = 0; j < 8; ++j)
                    Ws[lr][lk + j] = (n < N && (k0 + lk + j) < K) ? p[j] : (unsigned short)0;
            }
        }
        __syncthreads();
        frag_ab bfr = *(const frag_ab*)&Ws[wave * 16 + l16][q * 8];
        #pragma unroll
        for (int mb = 0; mb < 4; ++mb) {
            frag_ab afr = *(const frag_ab*)&Xs[mb * 16 + l16][q * 8];
            acc[mb] = __builtin_amdgcn_mfma_f32_16x16x32_bf16(afr, bfr, acc[mb], 0, 0, 0);
        }
        __syncthreads();
    }
    const int col = n0 + wave * 16 + l16;
    if (col < N) {
        float bv = 0.f;
        if (HAS_BIAS) bv = bias[col];
        #pragma unroll
        for (int mb = 0; mb < 4; ++mb) {
            #pragma unroll
            for (int r = 0; r < 4; ++r) {
                int row = m0 + mb * 16 + q * 4 + r;
                int orow = perm_row<PERM>(row);
                float v = acc[mb][r] + bv;
                if (ACT == 1) v = gelu_f(v);
                if (HAS_RES) v += b2f(res[(size_t)orow * ldr + col]);
                stv(&Y[(size_t)orow * ldy + col], v);
            }
        }
    }
}

// ---------------- window attention: one wave per (window, head) ----------------
// qkvw is WINDOW-ORDERED: row w64 = w*64 + t, cols [q:h*30+d][k:180+...][v:360+...]
// attn_out written window-ordered [BL][180].
// Thread i owns query row i: S-row (64 fp32) in registers -> softmax thread-local.
// k then v staged via one shared f32 buffer (broadcast reads, conflict-free).
__global__ __launch_bounds__(64) void attn_kernel(
    const unsigned short* __restrict__ qkvw,
    const float* __restrict__ b_rel,
    unsigned short* __restrict__ attn_out)
{
    __shared__ float kv[64][36];            // 9216 B; stride 36 floats (144 B, 16B-aligned rows)
    const int blk = blockIdx.x;             // 0..12287
    const int h = blk % 6;
    const int w = blk / 6;                  // 0..2047; row base = w*64 (window-ordered)
    const int lane = threadIdx.x;
    const float scale = 0.18257418583505536f;  // 30^-0.5

    const unsigned short* qrow = qkvw + (size_t)(w * 64 + lane) * 540 + h * 30;

    // q row -> registers (fp32)
    float q[30];
    #pragma unroll
    for (int d = 0; d < 15; ++d) {
        unsigned int u = *(const unsigned int*)(qrow + 2 * d);
        q[2 * d] = blo(u); q[2 * d + 1] = bhi(u);
    }
    // k row -> LDS (fp32)
    #pragma unroll
    for (int d = 0; d < 15; ++d) {
        unsigned int u = *(const unsigned int*)(qrow + 180 + 2 * d);
        kv[lane][2 * d] = blo(u); kv[lane][2 * d + 1] = bhi(u);
    }
    __syncthreads();

    // S row in registers
    float s[64];
    const float* br = b_rel + h * 4096 + lane * 64;
    #pragma unroll
    for (int j = 0; j < 64; ++j) {
        const float* kj = &kv[j][0];
        float acc = 0.f;
        #pragma unroll
        for (int d = 0; d < 30; ++d) acc += q[d] * kj[d];
        s[j] = acc * scale + br[j];
    }

    // thread-local softmax (unnormalized; fold 1/sum into output)
    float mx = -1e30f;
    #pragma unroll
    for (int j = 0; j < 64; ++j) mx = fmaxf(mx, s[j]);
    float sum = 0.f;
    #pragma unroll
    for (int j = 0; j < 64; ++j) { s[j] = __expf(s[j] - mx); sum += s[j]; }
    float inv = 1.f / sum;

    // v row -> LDS (reuse buffer)
    __syncthreads();
    #pragma unroll
    for (int d = 0; d < 15; ++d) {
        unsigned int u = *(const unsigned int*)(qrow + 360 + 2 * d);
        kv[lane][2 * d] = blo(u); kv[lane][2 * d + 1] = bhi(u);
    }
    __syncthreads();

    // O row = (P @ V) * inv
    float o[30];
    #pragma unroll
    for (int d = 0; d < 30; ++d) o[d] = 0.f;
    #pragma unroll
    for (int j = 0; j < 64; ++j) {
        const float* vj = &kv[j][0];
        float p = s[j];
        #pragma unroll
        for (int d = 0; d < 30; ++d) o[d] += p * vj[d];
    }
    unsigned short* orow = attn_out + (size_t)(w * 64 + lane) * CH + h * 30;
    #pragma unroll
    for (int d = 0; d < 15; ++d) {
        unsigned int u = (unsigned int)f2b(o[2 * d] * inv)
                       | ((unsigned int)f2b(o[2 * d + 1] * inv) << 16);
        *(unsigned int*)(orow + 2 * d) = u;
    }
}

// ---------------- depthwise 3x3 SAME conv, vectorized column-walk ----------------
template <int C, bool DO_GELU>
__global__ __launch_bounds__(256) void dwconv_kernel(
    const unsigned short* __restrict__ in, const float* __restrict__ wT,
    unsigned short* __restrict__ out)
{
    constexpr int NG = (C + 7) / 8;
    constexpr int TY = 8;
    int gid = blockIdx.x * 256 + threadIdx.x;
    int cg = gid % NG;
    int t  = gid / NG;
    int x  = t % IMG;
    int t2 = t / IMG;
    int yb = t2 & 31;
    int bi = t2 >> 5;
    if (bi >= BATCH) return;
    const int c0 = cg * 8;
    const int y0 = yb * TY;

    float w9[9][8];
    #pragma unroll
    for (int tp = 0; tp < 9; ++tp) {
        float4 wa = *(const float4*)&wT[tp * C + c0];
        float4 wb = *(const float4*)&wT[tp * C + c0 + 4];
        w9[tp][0]=wa.x; w9[tp][1]=wa.y; w9[tp][2]=wa.z; w9[tp][3]=wa.w;
        w9[tp][4]=wb.x; w9[tp][5]=wb.y; w9[tp][6]=wb.z; w9[tp][7]=wb.w;
    }

    unsigned int rr[3][3][4];

    auto load_row = [&](int y, unsigned int dst[3][4]) {
        if ((unsigned)y >= (unsigned)IMG) {
            #pragma unroll
            for (int cc = 0; cc < 3; ++cc)
                #pragma unroll
                for (int k = 0; k < 4; ++k) dst[cc][k] = 0u;
            return;
        }
        size_t base = ((size_t)((bi << 16) + (y << 8) + x)) * C + c0;
        #pragma unroll
        for (int cc = 0; cc < 3; ++cc) {
            int xx = x + cc - 1;
            if ((unsigned)xx >= (unsigned)IMG) {
                dst[cc][0] = dst[cc][1] = dst[cc][2] = dst[cc][3] = 0u;
                continue;
            }
            const unsigned short* p = in + base + (ptrdiff_t)(cc - 1) * C;
            uint2 u0 = *(const uint2*)p;
            uint2 u1 = *(const uint2*)(p + 4);
            dst[cc][0] = u0.x; dst[cc][1] = u0.y; dst[cc][2] = u1.x; dst[cc][3] = u1.y;
        }
    };

    load_row(y0 - 1, rr[0]);
    load_row(y0,     rr[1]);

    #pragma unroll
    for (int dy = 0; dy < TY; ++dy) {
        load_row(y0 + dy + 1, rr[(dy + 2) % 3]);
        float acc[8];
        #pragma unroll
        for (int j = 0; j < 8; ++j) acc[j] = 0.f;
        #pragma unroll
        for (int ky = 0; ky < 3; ++ky) {
            unsigned int (*row)[4] = rr[(dy + ky) % 3];
            #pragma unroll
            for (int kx = 0; kx < 3; ++kx) {
                const float* wp = w9[ky * 3 + kx];
                const unsigned int* u = row[kx];
                acc[0] += blo(u[0]) * wp[0];
                acc[1] += bhi(u[0]) * wp[1];
                acc[2] += blo(u[1]) * wp[2];
                acc[3] += bhi(u[1]) * wp[3];
                acc[4] += blo(u[2]) * wp[4];
                acc[5] += bhi(u[2]) * wp[5];
                acc[6] += blo(u[3]) * wp[6];
                acc[7] += bhi(u[3]) * wp[7];
            }
        }
        if (DO_GELU) {
            #pragma unroll
            for (int j = 0; j < 8; ++j) acc[j] = gelu_f(acc[j]);
        }
        size_t ob = ((size_t)((bi << 16) + ((y0 + dy) << 8) + x)) * C + c0;
        unsigned int o0 = (unsigned int)f2b(acc[0]) | ((unsigned int)f2b(acc[1]) << 16);
        unsigned int o1 = (unsigned int)f2b(acc[2]) | ((unsigned int)f2b(acc[3]) << 16);
        *(uint2*)(out + ob) = make_uint2(o0, o1);
        if (c0 + 8 <= C) {
            unsigned int o2 = (unsigned int)f2b(acc[4]) | ((unsigned int)f2b(acc[5]) << 16);
            unsigned int o3 = (unsigned int)f2b(acc[6]) | ((unsigned int)f2b(acc[7]) << 16);
            *(uint2*)(out + ob + 4) = make_uint2(o2, o3);
        }
    }
}

// ---------------- sum-pool over L per (b,c), ushort4 ----------------
__global__ __launch_bounds__(64) void pool_kernel(
    const unsigned short* __restrict__ cf, float* __restrict__ pooled)
{
    int t = threadIdx.x;
    if (t >= 45) return;
    int b = blockIdx.x >> 7;
    int chunk = blockIdx.x & 127;
    const unsigned short* base = cf + (size_t)(b * LTOK + chunk * 512) * CH + t * 4;
    float s0 = 0.f, s1 = 0.f, s2 = 0.f, s3 = 0.f;
    for (int i = 0; i < 512; ++i) {
        ushort4 v = *(const ushort4*)(base + (size_t)i * CH);
        s0 += b2f(v.x); s1 += b2f(v.y); s2 += b2f(v.z); s3 += b2f(v.w);
    }
    atomicAdd(&pooled[b * CH + t * 4 + 0], s0);
    atomicAdd(&pooled[b * CH + t * 4 + 1], s1);
    atomicAdd(&pooled[b * CH + t * 4 + 2], s2);
    atomicAdd(&pooled[b * CH + t * 4 + 3], s3);
}

// ---------------- channel gate ----------------
__global__ __launch_bounds__(256) void cm_kernel(
    const float* __restrict__ pooled, const float* __restrict__ w1,
    const float* __restrict__ w2, float* __restrict__ cm)
{
    __shared__ float p[BATCH][CH];
    __shared__ float g1[BATCH][22];
    int t = threadIdx.x;
    for (int idx = t; idx < BATCH * CH; idx += 256)
        p[idx / CH][idx % CH] = pooled[idx] * (1.f / (float)LTOK);
    __syncthreads();
    if (t < BATCH * 22) {
        int b = t / 22, u = t % 22;
        float s = 0.f;
        for (int c = 0; c < CH; ++c) s += p[b][c] * w1[u * CH + c];
        g1[b][u] = gelu_f(s);
    }
    __syncthreads();
    for (int idx = t; idx < BATCH * CH; idx += 256) {
        int b = idx / CH, c = idx % CH;
        float s = 0.f;
        for (int u = 0; u < 22; ++u) s += g1[b][u] * w2[c * 22 + u];
        cm[idx] = 1.f / (1.f + __expf(-s));
    }
}

// ---------------- residual 1, 4 channels/thread ----------------
__global__ __launch_bounds__(256) void resid_kernel(
    const float* __restrict__ x, const unsigned short* __restrict__ attn_feat,
    const unsigned short* __restrict__ conv_feat, const float* __restrict__ cm,
    unsigned short* __restrict__ x_mid)
{
    int gid = blockIdx.x * 256 + threadIdx.x;     // BL*CH/4 threads
    int c4 = gid % 45;
    int b = gid / (LTOK * 45);
    float4 xv = ((const float4*)x)[gid];
    ushort4 a = ((const ushort4*)attn_feat)[gid];
    ushort4 c = ((const ushort4*)conv_feat)[gid];
    float4 m = *(const float4*)&cm[b * CH + c4 * 4];
    unsigned int o0 = (unsigned int)f2b(xv.x + b2f(a.x) * m.x + b2f(c.x))
                    | ((unsigned int)f2b(xv.y + b2f(a.y) * m.y + b2f(c.y)) << 16);
    unsigned int o1 = (unsigned int)f2b(xv.z + b2f(a.z) * m.z + b2f(c.z))
                    | ((unsigned int)f2b(xv.w + b2f(a.w) * m.w + b2f(c.w)) << 16);
    ((uint2*)x_mid)[gid] = make_uint2(o0, o1);
}

// ---------------- launch ----------------
extern "C" void kernel_launch(void* const* d_in, const int* in_sizes, int n_in,
                              void* d_out, int out_size, void* d_ws, size_t ws_size,
                              hipStream_t stream)
{
    const float* x       = (const float*)d_in[0];
    const float* w_qkv   = (const float*)d_in[1];
    const float* b_rel   = (const float*)d_in[2];
    const float* w_proj  = (const float*)d_in[3];
    const float* b_proj  = (const float*)d_in[4];
    const float* conv_dw = (const float*)d_in[5];
    const float* cg_w1   = (const float*)d_in[6];
    const float* cg_w2   = (const float*)d_in[7];
    const float* ffn_w1  = (const float*)d_in[8];
    const float* ffn_dw  = (const float*)d_in[9];
    const float* ffn_w2  = (const float*)d_in[10];
    const float* n1_g    = (const float*)d_in[11];
    const float* n1_b    = (const float*)d_in[12];
    const float* n2_g    = (const float*)d_in[13];
    const float* n2_b    = (const float*)d_in[14];

    // ---- workspace layout (bytes), peak ~225.6 MiB ----
    char* ws = (char*)d_ws;
    unsigned short* n1        = (unsigned short*)(ws);                      // [0, 47.2MB)
    unsigned short* qkvw      = (unsigned short*)(ws + 47185920);           // [47.2, 188.7MB) window-ordered
    unsigned short* conv_feat = (unsigned short*)(ws + 188743680);          // [188.7, 235.9MB)
    unsigned short* attn_out  = (unsigned short*)(ws);                      // reuse n1 (window-ordered)
    unsigned short* attn_feat = (unsigned short*)(ws + 47185920);           // reuse qkv head (token order)
    unsigned short* x_mid     = (unsigned short*)(ws + 94371840);           // reuse qkv mid
    unsigned short* n2        = (unsigned short*)(ws + 141557760);          // reuse qkv tail
    unsigned short* h         = (unsigned short*)(ws);                      // [0, 94.4MB)
    unsigned short* h_s       = (unsigned short*)(ws + 141557760);          // [141.6, 235.9MB)
    float*          pooled    = (float*)(ws + 235929600);                   // 1440 B
    float*          cmv       = (float*)(ws + 235931040);                   // 1440 B
    unsigned short* wbf       = (unsigned short*)(ws + 235932480);          // 518,400 B
    float*          wT1       = (float*)(ws + 236450880);                   // 25,920 B
    float*          wT2       = (float*)(ws + 236476800);                   // 51,840 B
    unsigned short* wqkv_b  = wbf;
    unsigned short* wproj_b = wbf + 97200;
    unsigned short* wffn1_b = wbf + 129600;
    unsigned short* wffn2_b = wbf + 194400;
    float* out = (float*)d_out;

    hipMemsetAsync(pooled, 0, 2880, stream);

    // 0. weight prep
    convw_kernel<<<1089, 256, 0, stream>>>(w_qkv, w_proj, ffn_w1, ffn_w2,
                                           conv_dw, ffn_dw, wbf, wT1, wT2);
    // 1. LN1: x(fp32) -> n1(bf16)
    ln_kernel<float><<<BL / 4, 256, 0, stream>>>(x, n1_g, n1_b, n1);
    // 2. qkvw = n1 @ w_qkv^T, rows stored window-ordered (PERM=1)
    gemm_kernel<0, false, false, 1, unsigned short><<<dim3(BL / 64, 9), 256, 0, stream>>>(
        n1, CH, wqkv_b, nullptr, nullptr, 0, qkvw, 540, 540, CH);
    // 3. conv branch: gelu(dwconv3x3(n1)) -> conv_feat
    dwconv_kernel<CH, true><<<1472, 256, 0, stream>>>(n1, wT1, conv_feat);
    // 4. pooled = sum_L conv_feat
    pool_kernel<<<BATCH * 128, 64, 0, stream>>>(conv_feat, pooled);
    // 5. cm
    cm_kernel<<<1, 256, 0, stream>>>(pooled, cg_w1, cg_w2, cmv);
    // 6. window attention: one wave per (window, head)
    attn_kernel<<<2048 * 6, 64, 0, stream>>>(qkvw, b_rel, attn_out);
    // 7. attn_feat = attn_out @ w_proj^T + b_proj; X window-ordered, Y token order (PERM=2)
    gemm_kernel<0, true, false, 2, unsigned short><<<dim3(BL / 64, 3), 256, 0, stream>>>(
        attn_out, CH, wproj_b, b_proj, nullptr, 0, attn_feat, CH, CH, CH);
    // 8. x_mid = x + attn_feat*cm + conv_feat  (bf16)
    resid_kernel<<<(BL * CH / 4) / 256, 256, 0, stream>>>(x, attn_feat, conv_feat, cmv, x_mid);
    // 9. LN2
    ln_kernel<unsigned short><<<BL / 4, 256, 0, stream>>>(x_mid, n2_g, n2_b, n2);
    // 10. h = gelu(n2 @ ffn_w1^T)
    gemm_kernel<1, false, false, 0, unsigned short><<<dim3(BL / 64, 6), 256, 0, stream>>>(
        n2, CH, wffn1_b, nullptr, nullptr, 0, h, HDF, HDF, CH);
    // 11. h_s = dwconv3x3(h)
    dwconv_kernel<HDF, false><<<2880, 256, 0, stream>>>(h, wT2, h_s);
    // 12. out(fp32) = x_mid + h_s @ ffn_w2^T
    gemm_kernel<0, false, true, 0, float><<<dim3(BL / 64, 3), 256, 0, stream>>>(
        h_s, HDF, wffn2_b, nullptr, x_mid, CH, out, CH, CH, HDF);
}